// Round 6
// baseline (438.006 us; speedup 1.0000x reference)
//
#include <hip/hip_runtime.h>
#include <math.h>

// ---------------------------------------------------------------------------
// GIN, 3 layers, N=100000, E=1000000, D=64, fp32 in/out.
// Round 6:
//  - Fused k_layer: CSR gather (wave-private LDS A-tile, 16 nodes/wave)
//    + bf16x3 MFMA 2-layer MLP in one kernel. Kills the 25.6MB agg
//    store+reload per layer and 3 launches.
//  - Single k_pack_all launch for all 6 weight matrices.
//  - CSR build unchanged (k_fill known store-op-bound; binned fill is the
//    next candidate).
//  - Routing: x -> buf1 -> buf2 -> d_out.
// ---------------------------------------------------------------------------

#define FEAT 64

typedef __attribute__((ext_vector_type(8))) short bfrag;   // 8 bf16 (4 VGPRs)
typedef __attribute__((ext_vector_type(4))) float ffrag;   // 4 fp32 acc

__device__ __forceinline__ unsigned short f2bf_rne(float x) {
    union { float f; unsigned u; } v; v.f = x;
    unsigned r = (v.u + 0x7fffu + ((v.u >> 16) & 1u)) >> 16;
    return (unsigned short)r;
}
__device__ __forceinline__ float bf2f(unsigned short h) {
    union { unsigned u; float f; } v; v.u = ((unsigned)h) << 16;
    return v.f;
}

// ---------------- CSR build ------------------------------------------------
__global__ void k_zero(int* p, int n) {
    int i = blockIdx.x * 256 + threadIdx.x;
    if (i < n) p[i] = 0;
}

__global__ void k_hist(const int* __restrict__ dst, int* __restrict__ deg, int E) {
    int e = blockIdx.x * 256 + threadIdx.x;
    if (e < E) atomicAdd(&deg[dst[e]], 1);
}

__global__ void k_scan1(const int* __restrict__ deg, int* __restrict__ part,
                        int* __restrict__ bsums, int n) {
    __shared__ int tmp[256];
    int tid = threadIdx.x;
    int i = blockIdx.x * 256 + tid;
    int v = (i < n) ? deg[i] : 0;
    tmp[tid] = v;
    __syncthreads();
    for (int off = 1; off < 256; off <<= 1) {
        int t = (tid >= off) ? tmp[tid - off] : 0;
        __syncthreads();
        tmp[tid] += t;
        __syncthreads();
    }
    if (i < n) part[i] = tmp[tid] - v;            // exclusive
    if (tid == 255) bsums[blockIdx.x] = tmp[255]; // block total
}

__global__ void k_scan2(int* bsums, int nb) {
    __shared__ int tmp[512];
    int tid = threadIdx.x;
    int v = (tid < nb) ? bsums[tid] : 0;
    tmp[tid] = v;
    __syncthreads();
    for (int off = 1; off < 512; off <<= 1) {
        int t = (tid >= off) ? tmp[tid - off] : 0;
        __syncthreads();
        tmp[tid] += t;
        __syncthreads();
    }
    if (tid < nb) bsums[tid] = tmp[tid] - v;
}

__global__ void k_add(int* __restrict__ rowptr, int* __restrict__ pos,
                      const int* __restrict__ bsums, int n, int E) {
    int i = blockIdx.x * 256 + threadIdx.x;
    if (i < n) {
        int v = rowptr[i] + bsums[i >> 8];
        rowptr[i] = v;
        pos[i] = v;
    } else if (i == n) {
        rowptr[n] = E;
    }
}

__global__ void k_fill(const int* __restrict__ src, const int* __restrict__ dst,
                       const float* __restrict__ ew, int* __restrict__ pos,
                       int2* __restrict__ csr, int E) {
    int e = blockIdx.x * 256 + threadIdx.x;
    if (e < E) {
        int d = dst[e];
        int slot = atomicAdd(&pos[d], 1);
        csr[slot] = make_int2(src[e], __float_as_int(ew[e]));  // one 8B store
    }
}

// ---------------- weight pack (all 6 matrices, one launch) -----------------
__device__ __forceinline__ void pack_one(const float* __restrict__ w,
                                         unsigned short* __restrict__ hi,
                                         unsigned short* __restrict__ lo,
                                         int K, int Hc, int i) {
    int KF = K >> 5;
    int j    = i & 7;
    int lane = (i >> 3) & 63;
    int fb   = i >> 9;
    int kf   = fb % KF;
    int cg   = fb / KF;
    int k    = kf * 32 + ((lane >> 4) << 3) + j;
    int col  = cg * 16 + (lane & 15);
    float x = w[k * Hc + col];
    unsigned short h = f2bf_rne(x);
    hi[i] = h;
    lo[i] = f2bf_rne(x - bf2f(h));
}

__global__ void k_pack_all(const float* w11, const float* w12, const float* w21,
                           const float* w22, const float* w31, const float* w32,
                           unsigned short* p11h, unsigned short* p11l,
                           unsigned short* p12h, unsigned short* p12l,
                           unsigned short* p21h, unsigned short* p21l,
                           unsigned short* p22h, unsigned short* p22l,
                           unsigned short* p31h, unsigned short* p31l,
                           unsigned short* p32h, unsigned short* p32l) {
    int i = blockIdx.x * 256 + threadIdx.x;         // 0..32767
    if      (i <  4096) pack_one(w11, p11h, p11l,  64,  64, i);
    else if (i <  8192) pack_one(w12, p12h, p12l,  64,  64, i - 4096);
    else if (i < 16384) pack_one(w21, p21h, p21l,  64, 128, i - 8192);
    else if (i < 24576) pack_one(w22, p22h, p22l, 128,  64, i - 16384);
    else if (i < 28672) pack_one(w31, p31h, p31l,  64,  64, i - 24576);
    else                pack_one(w32, p32h, p32l,  64,  64, i - 28672);
}

// ---------------- fused layer: gather + bf16x3 MFMA MLP --------------------
// Block = 256 threads = 4 waves = 64 nodes; wave-private LDS tile of 16 nodes.
template<int H, bool RELU_OUT>
__global__ __launch_bounds__(256)
void k_layer(const float* __restrict__ in, float* __restrict__ out,
             const int* __restrict__ rowptr, const int2* __restrict__ csr,
             const unsigned short* __restrict__ w1h, const unsigned short* __restrict__ w1l,
             const float* __restrict__ b1,
             const unsigned short* __restrict__ w2h, const unsigned short* __restrict__ w2l,
             const float* __restrict__ b2, int N) {
    constexpr int SA    = 68;                         // A-tile stride (floats)
    constexpr int SH    = H + 4;                      // h-tile stride
    constexpr int WTILE = 16 * (SH > SA ? SH : SA);   // per-wave floats
    constexpr int CG1   = H / 16;                     // phase-1 col groups
    constexpr int KF2   = H / 32;                     // phase-2 k frags
    __shared__ float S[4 * WTILE];

    const int t    = threadIdx.x;
    const int wv   = t >> 6, lane = t & 63;
    const int qw   = lane >> 4;      // edge slot / k-chunk selector
    const int f    = lane & 15;      // feature quad / node-in-tile selector
    const int node0 = blockIdx.x * 64 + wv * 16;
    float* Sw = &S[wv * WTILE];
    const float4* in4 = reinterpret_cast<const float4*>(in);

    // ---- gather phase: 16 nodes sequentially per wave -> LDS A-tile ----
    for (int i = 0; i < 16; ++i) {
        const int node = node0 + i;                  // wave-uniform
        float4 acc = make_float4(0.f, 0.f, 0.f, 0.f);
        if (node < N) {
            const int beg = rowptr[node];
            const int end = rowptr[node + 1];
            float4 xr = in4[(size_t)node * 16 + f];  // "+x", issue early
            for (int p = beg; p < end; p += 16) {
                int   s[4];
                float w[4];
#pragma unroll
                for (int u = 0; u < 4; ++u) {
                    int idx = p + 4 * u + qw;
                    int2 ev = make_int2(0, 0);
                    if (idx < end) ev = csr[idx];    // one dwordx2
                    s[u] = ev.x;
                    w[u] = __int_as_float(ev.y);     // 0.0f when inactive
                }
                float4 v[4];
#pragma unroll
                for (int u = 0; u < 4; ++u)
                    v[u] = in4[(size_t)s[u] * 16 + f];   // 4 row-loads in flight
#pragma unroll
                for (int u = 0; u < 4; ++u) {
                    acc.x = fmaf(w[u], v[u].x, acc.x);
                    acc.y = fmaf(w[u], v[u].y, acc.y);
                    acc.z = fmaf(w[u], v[u].z, acc.z);
                    acc.w = fmaf(w[u], v[u].w, acc.w);
                }
            }
            // butterfly across the 4 edge-slots (lane bits 4,5)
            acc.x += __shfl_xor(acc.x, 16); acc.y += __shfl_xor(acc.y, 16);
            acc.z += __shfl_xor(acc.z, 16); acc.w += __shfl_xor(acc.w, 16);
            acc.x += __shfl_xor(acc.x, 32); acc.y += __shfl_xor(acc.y, 32);
            acc.z += __shfl_xor(acc.z, 32); acc.w += __shfl_xor(acc.w, 32);
            acc.x += xr.x; acc.y += xr.y; acc.z += xr.z; acc.w += xr.w;
        }
        if (qw == 0)
            *reinterpret_cast<float4*>(&Sw[i * SA + 4 * f]) = acc;  // zeros for tail
    }
    __syncthreads();

    // ---- A-frags (K=64 -> 2 kf) from LDS, split hi/lo ----
    const int m = f;                 // node within tile
    const int q = qw;                // k-chunk
    bfrag ah[2], al[2];
#pragma unroll
    for (int kf = 0; kf < 2; ++kf) {
        const float* base = &Sw[m * SA + kf * 32 + q * 8];
        float4 u0 = *reinterpret_cast<const float4*>(base);
        float4 u1 = *reinterpret_cast<const float4*>(base + 4);
        float u[8] = {u0.x, u0.y, u0.z, u0.w, u1.x, u1.y, u1.z, u1.w};
#pragma unroll
        for (int j = 0; j < 8; ++j) {
            unsigned short hb = f2bf_rne(u[j]);
            ah[kf][j] = (short)hb;
            al[kf][j] = (short)f2bf_rne(u[j] - bf2f(hb));
        }
    }
    __syncthreads();   // A-tile consumed -> safe to overlay h

    const bfrag* w1hp = reinterpret_cast<const bfrag*>(w1h);
    const bfrag* w1lp = reinterpret_cast<const bfrag*>(w1l);
    const bfrag* w2hp = reinterpret_cast<const bfrag*>(w2h);
    const bfrag* w2lp = reinterpret_cast<const bfrag*>(w2l);

    // ---- phase 1: h = relu(A@W1 + b1) -> LDS ----
#pragma unroll
    for (int cg = 0; cg < CG1; ++cg) {
        ffrag c = {0.f, 0.f, 0.f, 0.f};
#pragma unroll
        for (int kf = 0; kf < 2; ++kf) {
            bfrag bh = w1hp[(cg * 2 + kf) * 64 + lane];
            bfrag bl = w1lp[(cg * 2 + kf) * 64 + lane];
            c = __builtin_amdgcn_mfma_f32_16x16x32_bf16(ah[kf], bh, c, 0, 0, 0);
            c = __builtin_amdgcn_mfma_f32_16x16x32_bf16(al[kf], bh, c, 0, 0, 0);
            c = __builtin_amdgcn_mfma_f32_16x16x32_bf16(ah[kf], bl, c, 0, 0, 0);
        }
        float bias = b1[cg * 16 + m];
#pragma unroll
        for (int r = 0; r < 4; ++r) {
            float hv = fmaxf(c[r] + bias, 0.f);
            Sw[(q * 4 + r) * SH + cg * 16 + m] = hv;   // row=node, col=h-col
        }
    }
    __syncthreads();

    // ---- h -> A frags (hi/lo) ----
    bfrag gh[KF2], gl[KF2];
#pragma unroll
    for (int kf = 0; kf < KF2; ++kf) {
        const float* base = &Sw[m * SH + kf * 32 + q * 8];
        float4 u0 = *reinterpret_cast<const float4*>(base);
        float4 u1 = *reinterpret_cast<const float4*>(base + 4);
        float u[8] = {u0.x, u0.y, u0.z, u0.w, u1.x, u1.y, u1.z, u1.w};
#pragma unroll
        for (int j = 0; j < 8; ++j) {
            unsigned short hb = f2bf_rne(u[j]);
            gh[kf][j] = (short)hb;
            gl[kf][j] = (short)f2bf_rne(u[j] - bf2f(hb));
        }
    }

    // ---- phase 2: out = h@W2 + b2 ----
#pragma unroll
    for (int cg = 0; cg < 4; ++cg) {
        ffrag c = {0.f, 0.f, 0.f, 0.f};
#pragma unroll
        for (int kf = 0; kf < KF2; ++kf) {
            bfrag bh = w2hp[(cg * KF2 + kf) * 64 + lane];
            bfrag bl = w2lp[(cg * KF2 + kf) * 64 + lane];
            c = __builtin_amdgcn_mfma_f32_16x16x32_bf16(gh[kf], bh, c, 0, 0, 0);
            c = __builtin_amdgcn_mfma_f32_16x16x32_bf16(gl[kf], bh, c, 0, 0, 0);
            c = __builtin_amdgcn_mfma_f32_16x16x32_bf16(gh[kf], bl, c, 0, 0, 0);
        }
        float bias = b2[cg * 16 + m];
#pragma unroll
        for (int r = 0; r < 4; ++r) {
            int nd = node0 + q * 4 + r;
            if (nd < N) {
                float v = c[r] + bias;
                if (RELU_OUT) v = fmaxf(v, 0.f);
                out[(size_t)nd * FEAT + cg * 16 + m] = v;
            }
        }
    }
}

// ---------------------------------------------------------------------------
extern "C" void kernel_launch(void* const* d_in, const int* in_sizes, int n_in,
                              void* d_out, int out_size, void* d_ws, size_t ws_size,
                              hipStream_t stream) {
    const float* x   = (const float*)d_in[0];
    const int*   ei  = (const int*)  d_in[1];
    const float* ew  = (const float*)d_in[2];
    const float* w11 = (const float*)d_in[3];
    const float* b11 = (const float*)d_in[4];
    const float* w12 = (const float*)d_in[5];
    const float* b12 = (const float*)d_in[6];
    const float* w21 = (const float*)d_in[7];
    const float* b21 = (const float*)d_in[8];
    const float* w22 = (const float*)d_in[9];
    const float* b22 = (const float*)d_in[10];
    const float* w31 = (const float*)d_in[11];
    const float* b31 = (const float*)d_in[12];
    const float* w32 = (const float*)d_in[13];
    const float* b32 = (const float*)d_in[14];

    const int N = in_sizes[0] / FEAT;   // 100000
    const int E = in_sizes[2];          // 1000000
    const int* srci = ei;
    const int* dsti = ei + E;

    // ---- workspace layout ----
    float* buf1   = (float*)d_ws;                       // [N*64] layer-1 out
    float* buf2   = buf1 + (size_t)N * FEAT;            // [N*64] layer-2 out
    int*   rowptr = (int*)(buf2 + (size_t)N * FEAT);    // [N+1]
    int*   pos    = rowptr + (N + 1);                   // [N]
    int*   deg    = pos + N;                            // [N]
    int*   bsums  = deg + N;                            // [512]
    size_t c8 = ((size_t)(bsums + 512) + 7) & ~(size_t)7;
    int2*  csr    = (int2*)c8;                          // [E] interleaved (s,w)
    size_t pk = ((size_t)(csr + E) + 15) & ~(size_t)15;
    unsigned short* p11h = (unsigned short*)pk;         // 4096 each for 64x64
    unsigned short* p11l = p11h + 4096;
    unsigned short* p12h = p11l + 4096;
    unsigned short* p12l = p12h + 4096;
    unsigned short* p21h = p12l + 4096;                 // 8192 for 64x128
    unsigned short* p21l = p21h + 8192;
    unsigned short* p22h = p21l + 8192;                 // 8192 for 128x64
    unsigned short* p22l = p22h + 8192;
    unsigned short* p31h = p22l + 8192;
    unsigned short* p31l = p31h + 4096;
    unsigned short* p32h = p31l + 4096;
    unsigned short* p32l = p32h + 4096;
    float* outF   = (float*)d_out;                      // [N*64]

    const int gE   = (E + 255) / 256;
    const int gN   = (N + 255) / 256;
    const int nb1  = (N + 255) / 256;
    const int gN1  = (N + 1 + 255) / 256;
    const int gLay = (N + 63) / 64;

    // ---- CSR build ----
    k_zero <<<gN,  256, 0, stream>>>(deg, N);
    k_hist <<<gE,  256, 0, stream>>>(dsti, deg, E);
    k_scan1<<<nb1, 256, 0, stream>>>(deg, rowptr, bsums, N);
    k_scan2<<<1,   512, 0, stream>>>(bsums, nb1);
    k_add  <<<gN1, 256, 0, stream>>>(rowptr, pos, bsums, N, E);
    k_fill <<<gE,  256, 0, stream>>>(srci, dsti, ew, pos, csr, E);

    // ---- pack all weights (frag order, bf16 hi/lo), one launch ----
    k_pack_all<<<128, 256, 0, stream>>>(w11, w12, w21, w22, w31, w32,
                                        p11h, p11l, p12h, p12l, p21h, p21l,
                                        p22h, p22l, p31h, p31l, p32h, p32l);

    // ---- 3 fused layers: x -> buf1 -> buf2 -> d_out ----
    k_layer<64,  true ><<<gLay, 256, 0, stream>>>(x,    buf1, rowptr, csr,
                                                  p11h, p11l, b11, p12h, p12l, b12, N);
    k_layer<128, true ><<<gLay, 256, 0, stream>>>(buf1, buf2, rowptr, csr,
                                                  p21h, p21l, b21, p22h, p22l, b22, N);
    k_layer<64,  false><<<gLay, 256, 0, stream>>>(buf2, outF, rowptr, csr,
                                                  p31h, p31l, b31, p32h, p32l, b32, N);
}